// Round 4
// baseline (541.703 us; speedup 1.0000x reference)
//
#include <hip/hip_runtime.h>

#define S 128
#define N 32
#define D 300
#define DP 320
#define E 64
#define R 4
#define V 50000
#define VP 50048
#define ND 9600
#define KY 1504   // stacked K for P0 GEMM: 4*300 conv + 300 W0 + 4 pad
#define DPAD 304  // padded N rows for Bt matrices

typedef unsigned short ushortT;
typedef __attribute__((ext_vector_type(8))) short short8;
typedef __attribute__((ext_vector_type(4))) short short4v;
typedef __attribute__((ext_vector_type(4))) float floatx4;

__device__ inline float bf2f(ushortT h) {
    unsigned u = ((unsigned)h) << 16;
    float f;
    __builtin_memcpy(&f, &u, 4);
    return f;
}

__device__ inline ushortT f2bf(float f) {
    unsigned u;
    __builtin_memcpy(&u, &f, 4);
    unsigned r = (u + 0x7fffu + ((u >> 16) & 1u)) >> 16;
    return (ushortT)r;
}

__device__ inline float ldf(const void* p, size_t i, int isb) {
    return isb ? bf2f(((const ushortT*)p)[i]) : ((const float*)p)[i];
}

__device__ inline float rdlane(float v, int lane) {
    int iv;
    __builtin_memcpy(&iv, &v, 4);
    int r = __builtin_amdgcn_readlane(iv, lane);
    float f;
    __builtin_memcpy(&f, &r, 4);
    return f;
}

// ---------------- K_detect: decide input dtype ------------------------------
__global__ void k_detect(const void* X, int* flag) {
    __shared__ int bad;
    if (threadIdx.x == 0) bad = 0;
    __syncthreads();
    const ushortT* p = (const ushortT*)X;
    int b = 0;
    for (int i = threadIdx.x; i < 4096; i += 256) {
        float v = bf2f(p[i]);
        if (!(v > -2.f && v < 2.f)) b = 1;  // catches NaN/Inf too
    }
    if (b) atomicOr(&bad, 1);
    __syncthreads();
    if (threadIdx.x == 0) flag[0] = bad ? 0 : 1;
}

// ---------------- K1: gather gxb[sn][d] = bf16(X[idx[sn]][d]) ---------------
__global__ void k_gatherb(const int* __restrict__ flag, const int* __restrict__ xi,
                          const void* __restrict__ X, ushortT* __restrict__ gxb) {
    int isb = flag[0];
    int sn = blockIdx.x;
    int d = threadIdx.x;
    if (d < D) {
        int node = xi[sn];
        ushortT v = isb ? ((const ushortT*)X)[(size_t)node * D + d]
                        : f2bf(((const float*)X)[(size_t)node * D + d]);
        gxb[(size_t)sn * D + d] = v;
    }
}

// ---------------- K2: transpose Wg [9600,300] -> wgt [304,9600] bf16 --------
__global__ void k_twg(const int* __restrict__ flag, const void* __restrict__ Wg,
                      ushortT* __restrict__ wgt) {
    int isb = flag[0];
    __shared__ float tile[32][33];
    int k0 = blockIdx.x * 32, d0 = blockIdx.y * 32;
    int tx = threadIdx.x & 31, ty = threadIdx.x >> 5;  // 32x8
    for (int i = ty; i < 32; i += 8) {
        int d = d0 + tx;
        tile[i][tx] = (d < D) ? ldf(Wg, (size_t)(k0 + i) * D + d, isb) : 0.f;
    }
    __syncthreads();
    for (int i = ty; i < 32; i += 8) {
        int d = d0 + i;
        if (d < DPAD) wgt[(size_t)d * ND + k0 + tx] = f2bf(tile[tx][i]);
    }
}

// ---------------- K3: build wst [304,1504] bf16 from convW|W0 stacked -------
__global__ void k_tws(const int* __restrict__ flag, const void* __restrict__ convW,
                      const void* __restrict__ W0, ushortT* __restrict__ wst) {
    int isb = flag[0];
    __shared__ float tile[32][33];
    int k0 = blockIdx.x * 32, d0 = blockIdx.y * 32;
    int tx = threadIdx.x & 31, ty = threadIdx.x >> 5;
    for (int i = ty; i < 32; i += 8) {
        int kp = k0 + i, d = d0 + tx;
        float v = 0.f;
        if (d < D && kp < 1500)
            v = (kp < 1200) ? ldf(convW, (size_t)kp * D + d, isb)
                            : ldf(W0, (size_t)(kp - 1200) * D + d, isb);
        tile[i][tx] = v;
    }
    __syncthreads();
    for (int i = ty; i < 32; i += 8) {
        int d = d0 + i;
        if (d < DPAD) wst[(size_t)d * KY + k0 + tx] = f2bf(tile[tx][i]);
    }
}

// ---------------- K4: build yb [128,1504] bf16 (graph-weighted row sums) ----
__global__ void k_yb(const ushortT* __restrict__ gxb, const int* __restrict__ ei,
                     const int* __restrict__ et, ushortT* __restrict__ yb) {
    int s = blockIdx.x;
    int t = threadIdx.x;  // 320
    __shared__ int se[E], de[E], te[E];
    __shared__ float disv[R][N];
    if (t < E) {
        se[t] = ei[(size_t)s * 2 * E + t];
        de[t] = ei[(size_t)s * 2 * E + E + t];
        te[t] = et[(size_t)s * E + t];
    }
    __syncthreads();
    if (t < R * N) {
        int r = t >> 5, n = t & 31;
        float c = 1.f;
        for (int e = 0; e < E; ++e) c += (te[e] == r && de[e] == n) ? 1.f : 0.f;
        disv[r][n] = rsqrtf(c);
    }
    __syncthreads();
    if (t < D) {
        const ushortT* g = gxb + (size_t)s * ND;
        float g0 = bf2f(g[t]);
        float yy[R];
#pragma unroll
        for (int r = 0; r < R; ++r) yy[r] = g0 * disv[r][0] * disv[r][0];
        for (int e = 0; e < E; ++e) {
            if (de[e] == 0) {
                int r = te[e];
                yy[r] += disv[r][se[e]] * disv[r][0] * bf2f(g[(size_t)se[e] * D + t]);
            }
        }
#pragma unroll
        for (int r = 0; r < R; ++r) yb[(size_t)s * KY + r * D + t] = f2bf(yy[r]);
        yb[(size_t)s * KY + 4 * D + t] = g[t];  // gx0 slot for W0
    }
    if (t < 4) yb[(size_t)s * KY + 1500 + t] = 0;
}

// ---------------- K5: GEMM partial over K-range (z-split) -------------------
// C[z][m][n] = sum_{k in z-slice} A[m][k]*Bt[n][k]; grid (M/16, NT, NZ).
__global__ __launch_bounds__(256) void k_gemm(const ushortT* __restrict__ A, int lda,
                                              const ushortT* __restrict__ Bt, int ldb,
                                              float* __restrict__ C, int ldc, int ncols,
                                              int kchunks, int per) {
    int wave = threadIdx.x >> 6, lane = threadIdx.x & 63;
    int col = lane & 15, quad = lane >> 4;
    int m0 = blockIdx.x * 16, n0 = blockIdx.y * 16;
    int z = blockIdx.z;
    int kbeg = z * per;
    int kend = kbeg + per;
    if (kend > kchunks) kend = kchunks;
    floatx4 acc = {0.f, 0.f, 0.f, 0.f};
    const ushortT* ap = A + (size_t)(m0 + col) * lda + quad * 8;
    const ushortT* bp = Bt + (size_t)(n0 + col) * ldb + quad * 8;
    for (int kc = kbeg + wave; kc < kend; kc += 4) {
        short8 a = *(const short8*)(ap + kc * 32);
        short8 b = *(const short8*)(bp + kc * 32);
        acc = __builtin_amdgcn_mfma_f32_16x16x32_bf16(a, b, acc, 0, 0, 0);
    }
    __shared__ float red[4][64][4];
#pragma unroll
    for (int i = 0; i < 4; ++i) red[wave][lane][i] = acc[i];
    __syncthreads();
    if (wave == 0) {
#pragma unroll
        for (int i = 0; i < 4; ++i) {
            float v = red[0][lane][i] + red[1][lane][i] + red[2][lane][i] + red[3][lane][i];
            int m = m0 + quad * 4 + i;
            int n = n0 + col;
            if (n < ncols) C[(size_t)z * S * ldc + (size_t)m * ldc + n] = v;
        }
    }
}

// ---------------- K5b: sum nz partials ----------------------------------------
__global__ void k_red(const float* __restrict__ part, float* __restrict__ out, int n, int nz) {
    int i = blockIdx.x * 256 + threadIdx.x;
    if (i < n) {
        float v = 0.f;
        for (int z = 0; z < nz; ++z) v += part[(size_t)z * n + i];
        out[i] = v;
    }
}

// ---------------- K6: sequential scan, readlane matvec ----------------------
// 512 thr = 8 waves pinned at 2 waves/EU so ug[5][38] (190 fp32) stays in
// registers (round-3 lesson: __launch_bounds__(512,2) alone let RA target
// 4 waves/EU -> 108 VGPRs + scratch spill).
__global__ __attribute__((amdgpu_flat_work_group_size(512, 512), amdgpu_waves_per_eu(2, 2))) void
k_scan(const int* __restrict__ flag, const float* __restrict__ a, const float* __restrict__ P0,
       const void* __restrict__ Ug, ushortT* __restrict__ x1p) {
    int isb = flag[0];
    int t = threadIdx.x;
    int w = t >> 6, lane = t & 63;
    float ug[5][38];
#pragma unroll
    for (int p = 0; p < 5; ++p) {
#pragma unroll
        for (int j = 0; j < 38; ++j) {
            int k = w * 38 + j, d = 64 * p + lane;
            ug[p][j] = (k < D && d < D) ? ldf(Ug, (size_t)k * D + d, isb) : 0.f;
        }
    }
    __shared__ float msh[336];
    __shared__ float part[8][320];
    for (int i = t; i < 336; i += 512) msh[i] = 0.f;
    float mreg = 0.f;  // m[t] for t<320 (persists across steps)
    __syncthreads();
    for (int s = 0; s < S; ++s) {
        // hoisted loads: consumed only after the matvec (latency hidden)
        float av = 0.f, pv = 0.f;
        if (t < D) {
            av = a[s * D + t];
            pv = P0[s * D + t];
        }
        float chunk = msh[w * 38 + lane];  // max idx 7*38+63=329 < 336 (zero pad)
        float acc0 = 0.f, acc1 = 0.f, acc2 = 0.f, acc3 = 0.f, acc4 = 0.f;
#pragma unroll
        for (int j = 0; j < 38; ++j) {
            float sm = rdlane(chunk, j);
            acc0 = fmaf(sm, ug[0][j], acc0);
            acc1 = fmaf(sm, ug[1][j], acc1);
            acc2 = fmaf(sm, ug[2][j], acc2);
            acc3 = fmaf(sm, ug[3][j], acc3);
            acc4 = fmaf(sm, ug[4][j], acc4);
        }
        part[w][lane] = acc0;
        part[w][64 + lane] = acc1;
        part[w][128 + lane] = acc2;
        part[w][192 + lane] = acc3;
        part[w][256 + lane] = acc4;
        __syncthreads();
        if (t < 320) {
            float pr = part[0][t] + part[1][t] + part[2][t] + part[3][t] + part[4][t] +
                       part[5][t] + part[6][t] + part[7][t];
            if (t < D) {
                float pre = av + pr;
                float u = 1.f / (1.f + __expf(-pre));
                float nm = u * pv + (1.f - u) * mreg;
                mreg = nm;
                msh[t] = nm;
                float x = nm > 0.f ? nm : 0.01f * nm;
                x1p[(size_t)s * DP + t] = f2bf(x);
            } else {
                x1p[(size_t)s * DP + t] = 0;
            }
        }
        __syncthreads();
    }
}

// ---------------- K7: logits = x1 @ lin_w^T + b via MFMA --------------------
__global__ __launch_bounds__(256) void k_logits(const int* __restrict__ flag,
                                                const ushortT* __restrict__ x1p,
                                                const void* __restrict__ lw,
                                                const void* __restrict__ lb,
                                                void* __restrict__ out) {
    int isb = flag[0];
    int wave = threadIdx.x >> 6, lane = threadIdx.x & 63;
    int col = lane & 15, quad = lane >> 4;
    int v = blockIdx.x * 64 + wave * 16 + col;
    int vv = v < V ? v : V - 1;
    floatx4 acc[8];
#pragma unroll
    for (int i = 0; i < 8; ++i) acc[i] = (floatx4){0.f, 0.f, 0.f, 0.f};
#pragma unroll
    for (int kc = 0; kc < 9; ++kc) {
        int k0 = kc * 32 + quad * 8;
        short8 b;
        if (isb) {
            const ushortT* bp = (const ushortT*)lw + (size_t)vv * D + k0;  // 8B aligned
            short4v lo = *(const short4v*)bp;
            short4v hi = *(const short4v*)(bp + 4);
            b = (short8){lo[0], lo[1], lo[2], lo[3], hi[0], hi[1], hi[2], hi[3]};
        } else {
            const float* bp = (const float*)lw + (size_t)vv * D + k0;  // 16B aligned
            floatx4 f0 = *(const floatx4*)bp;
            floatx4 f1 = *(const floatx4*)(bp + 4);
            b = (short8){(short)f2bf(f0[0]), (short)f2bf(f0[1]), (short)f2bf(f0[2]),
                         (short)f2bf(f0[3]), (short)f2bf(f1[0]), (short)f2bf(f1[1]),
                         (short)f2bf(f1[2]), (short)f2bf(f1[3])};
        }
#pragma unroll
        for (int st = 0; st < 8; ++st) {
            short8 aa = *(const short8*)(x1p + (size_t)(st * 16 + col) * DP + k0);
            acc[st] = __builtin_amdgcn_mfma_f32_16x16x32_bf16(aa, b, acc[st], 0, 0, 0);
        }
    }
    {  // tail chunk k=288..319 (lin_w valid only k<300; x1p zero-padded)
        int k0 = 288 + quad * 8;
        short8 b;
#pragma unroll
        for (int j = 0; j < 8; ++j) {
            int k = k0 + j;
            ushortT bv = 0;
            if (k < D)
                bv = isb ? ((const ushortT*)lw)[(size_t)vv * D + k]
                         : f2bf(((const float*)lw)[(size_t)vv * D + k]);
            b[j] = (short)bv;
        }
#pragma unroll
        for (int st = 0; st < 8; ++st) {
            short8 aa = *(const short8*)(x1p + (size_t)(st * 16 + col) * DP + k0);
            acc[st] = __builtin_amdgcn_mfma_f32_16x16x32_bf16(aa, b, acc[st], 0, 0, 0);
        }
    }
    if (v < V) {
        float bias = ldf(lb, v, isb);
#pragma unroll
        for (int st = 0; st < 8; ++st) {
#pragma unroll
            for (int i = 0; i < 4; ++i) {
                int s = st * 16 + quad * 4 + i;
                float val = acc[st][i] + bias;
                if (isb)
                    ((ushortT*)out)[(size_t)s * V + v] = f2bf(val);
                else
                    ((float*)out)[(size_t)s * V + v] = val;
            }
        }
    }
}

// ---------------- K8: per-row logsumexp -------------------------------------
__global__ void k_stats(const int* __restrict__ flag, const void* __restrict__ out,
                        float* __restrict__ stats) {
    int isb = flag[0];
    int s = blockIdx.x;
    int t = threadIdx.x;
    __shared__ float red[512];
    float mx = -1e30f;
    for (int v = t; v < V; v += 512) {
        float x = isb ? bf2f(((const ushortT*)out)[(size_t)s * V + v])
                      : ((const float*)out)[(size_t)s * V + v];
        mx = fmaxf(mx, x);
    }
    red[t] = mx;
    __syncthreads();
    for (int o = 256; o > 0; o >>= 1) {
        if (t < o) red[t] = fmaxf(red[t], red[t + o]);
        __syncthreads();
    }
    float M = red[0];
    __syncthreads();
    float sm = 0.f;
    for (int v = t; v < V; v += 512) {
        float x = isb ? bf2f(((const ushortT*)out)[(size_t)s * V + v])
                      : ((const float*)out)[(size_t)s * V + v];
        sm += __expf(x - M);
    }
    red[t] = sm;
    __syncthreads();
    for (int o = 256; o > 0; o >>= 1) {
        if (t < o) red[t] += red[t + o];
        __syncthreads();
    }
    if (t == 0) stats[s] = M + __logf(red[0]);
}

// ---------------- K9: normalize in place + zero senses tail -----------------
__global__ void k_final(const int* __restrict__ flag, void* __restrict__ out,
                        const float* __restrict__ stats) {
    int isb = flag[0];
    int s = blockIdx.y;
    int v = blockIdx.x * 256 + threadIdx.x;
    if (v < V) {
        size_t i = (size_t)s * V + v;
        if (isb) {
            ushortT* o = (ushortT*)out;
            o[i] = f2bf(bf2f(o[i]) - stats[s]);
        } else {
            float* o = (float*)out;
            o[i] = o[i] - stats[s];
        }
    }
    if (blockIdx.y == 0 && blockIdx.x == 0 && threadIdx.x < S) {
        if (isb)
            ((ushortT*)out)[(size_t)S * V + threadIdx.x] = 0;
        else
            ((float*)out)[(size_t)S * V + threadIdx.x] = 0.f;
    }
}

// ---------------- workspace layout (bytes, all 256-aligned) -----------------
#define OFF_FLAG 0
#define OFF_GXB 256
#define OFF_WGT 2457856
#define OFF_WST 8294656
#define OFF_YB 9209088
#define OFF_A 9594112
#define OFF_P0 9747712
#define OFF_X1P 9901312
#define OFF_STATS 9983232
#define OFF_PART 9983744  // optional z-split partial buffers (needs bigger ws)
#define PART_A_BYTES (4 * S * D * 4)
#define PART_P_BYTES (2 * S * D * 4)

extern "C" void kernel_launch(void* const* d_in, const int* in_sizes, int n_in, void* d_out,
                              int out_size, void* d_ws, size_t ws_size, hipStream_t stream) {
    const int* xi = (const int*)d_in[0];
    const int* ei = (const int*)d_in[1];
    const int* et = (const int*)d_in[2];
    const void* X = d_in[3];
    const void* convW = d_in[4];
    const void* W0 = d_in[5];
    const void* Wg = d_in[6];
    const void* Ug = d_in[7];
    const void* lw = d_in[8];
    const void* lb = d_in[9];
    char* ws = (char*)d_ws;

    int* flag = (int*)(ws + OFF_FLAG);
    ushortT* gxb = (ushortT*)(ws + OFF_GXB);
    ushortT* wgt = (ushortT*)(ws + OFF_WGT);
    ushortT* wst = (ushortT*)(ws + OFF_WST);
    ushortT* yb = (ushortT*)(ws + OFF_YB);
    float* a = (float*)(ws + OFF_A);
    float* P0 = (float*)(ws + OFF_P0);
    ushortT* x1p = (ushortT*)(ws + OFF_X1P);
    float* stats = (float*)(ws + OFF_STATS);

    // z-split K only if workspace is big enough for partial buffers
    bool split = ws_size >= (size_t)(OFF_PART + PART_A_BYTES + PART_P_BYTES);
    int nza = split ? 4 : 1;
    int nzp = split ? 2 : 1;
    float* apart = split ? (float*)(ws + OFF_PART) : a;
    float* ppart = split ? (float*)(ws + OFF_PART + PART_A_BYTES) : P0;
    int pera = (ND / 32 + nza - 1) / nza;
    int perp = (KY / 32 + nzp - 1) / nzp;

    hipLaunchKernelGGL(k_detect, dim3(1), dim3(256), 0, stream, X, flag);
    hipLaunchKernelGGL(k_gatherb, dim3(S * N), dim3(DP), 0, stream, flag, xi, X, gxb);
    hipLaunchKernelGGL(k_twg, dim3(ND / 32, 10), dim3(256), 0, stream, flag, Wg, wgt);
    hipLaunchKernelGGL(k_tws, dim3(KY / 32, 10), dim3(256), 0, stream, flag, convW, W0, wst);
    hipLaunchKernelGGL(k_yb, dim3(S), dim3(DP), 0, stream, gxb, ei, et, yb);
    hipLaunchKernelGGL(k_gemm, dim3(S / 16, 19, nza), dim3(256), 0, stream, gxb, ND, wgt, ND,
                       apart, D, D, ND / 32, pera);
    if (split)
        hipLaunchKernelGGL(k_red, dim3((S * D + 255) / 256), dim3(256), 0, stream, apart, a,
                           S * D, nza);
    hipLaunchKernelGGL(k_gemm, dim3(S / 16, 19, nzp), dim3(256), 0, stream, yb, KY, wst, KY,
                       ppart, D, D, KY / 32, perp);
    if (split)
        hipLaunchKernelGGL(k_red, dim3((S * D + 255) / 256), dim3(256), 0, stream, ppart, P0,
                           S * D, nzp);
    hipLaunchKernelGGL(k_scan, dim3(1), dim3(512), 0, stream, flag, a, P0, Ug, x1p);
    hipLaunchKernelGGL(k_logits, dim3(VP / 64), dim3(256), 0, stream, flag, x1p, lw, lb, d_out);
    hipLaunchKernelGGL(k_stats, dim3(S), dim3(512), 0, stream, flag, d_out, stats);
    hipLaunchKernelGGL(k_final, dim3((V + 255) / 256, S), dim3(256), 0, stream, flag, d_out, stats);
}

// Round 5
// 464.261 us; speedup vs baseline: 1.1668x; 1.1668x over previous
//
#include <hip/hip_runtime.h>

#define S 128
#define N 32
#define D 300
#define DP 320
#define E 64
#define R 4
#define V 50000
#define VP 50048
#define ND 9600
#define KY 1504   // stacked K for P0 GEMM: 4*300 conv + 300 W0 + 4 pad
#define DPAD 304  // padded N rows for Bt matrices

typedef unsigned short ushortT;
typedef __attribute__((ext_vector_type(8))) short short8;
typedef __attribute__((ext_vector_type(4))) short short4v;
typedef __attribute__((ext_vector_type(4))) float floatx4;

__device__ inline float bf2f(ushortT h) {
    unsigned u = ((unsigned)h) << 16;
    float f;
    __builtin_memcpy(&f, &u, 4);
    return f;
}

__device__ inline float bfbits_lo(unsigned u) {  // low ushort of packed pair
    unsigned b = u << 16;
    float f;
    __builtin_memcpy(&f, &b, 4);
    return f;
}

__device__ inline float bfbits_hi(unsigned u) {  // high ushort of packed pair
    unsigned b = u & 0xffff0000u;
    float f;
    __builtin_memcpy(&f, &b, 4);
    return f;
}

__device__ inline ushortT f2bf(float f) {
    unsigned u;
    __builtin_memcpy(&u, &f, 4);
    unsigned r = (u + 0x7fffu + ((u >> 16) & 1u)) >> 16;
    return (ushortT)r;
}

__device__ inline float ldf(const void* p, size_t i, int isb) {
    return isb ? bf2f(((const ushortT*)p)[i]) : ((const float*)p)[i];
}

__device__ inline float rdlane(float v, int lane) {
    int iv;
    __builtin_memcpy(&iv, &v, 4);
    int r = __builtin_amdgcn_readlane(iv, lane);
    float f;
    __builtin_memcpy(&f, &r, 4);
    return f;
}

// ---------------- K_detect: decide input dtype ------------------------------
__global__ void k_detect(const void* X, int* flag) {
    __shared__ int bad;
    if (threadIdx.x == 0) bad = 0;
    __syncthreads();
    const ushortT* p = (const ushortT*)X;
    int b = 0;
    for (int i = threadIdx.x; i < 4096; i += 256) {
        float v = bf2f(p[i]);
        if (!(v > -2.f && v < 2.f)) b = 1;  // catches NaN/Inf too
    }
    if (b) atomicOr(&bad, 1);
    __syncthreads();
    if (threadIdx.x == 0) flag[0] = bad ? 0 : 1;
}

// ---------------- K1: gather gxb[sn][d] = bf16(X[idx[sn]][d]) ---------------
__global__ void k_gatherb(const int* __restrict__ flag, const int* __restrict__ xi,
                          const void* __restrict__ X, ushortT* __restrict__ gxb) {
    int isb = flag[0];
    int sn = blockIdx.x;
    int d = threadIdx.x;
    if (d < D) {
        int node = xi[sn];
        ushortT v = isb ? ((const ushortT*)X)[(size_t)node * D + d]
                        : f2bf(((const float*)X)[(size_t)node * D + d]);
        gxb[(size_t)sn * D + d] = v;
    }
}

// ---------------- K2: transpose Wg [9600,300] -> wgt [304,9600] bf16 --------
__global__ void k_twg(const int* __restrict__ flag, const void* __restrict__ Wg,
                      ushortT* __restrict__ wgt) {
    int isb = flag[0];
    __shared__ float tile[32][33];
    int k0 = blockIdx.x * 32, d0 = blockIdx.y * 32;
    int tx = threadIdx.x & 31, ty = threadIdx.x >> 5;  // 32x8
    for (int i = ty; i < 32; i += 8) {
        int d = d0 + tx;
        tile[i][tx] = (d < D) ? ldf(Wg, (size_t)(k0 + i) * D + d, isb) : 0.f;
    }
    __syncthreads();
    for (int i = ty; i < 32; i += 8) {
        int d = d0 + i;
        if (d < DPAD) wgt[(size_t)d * ND + k0 + tx] = f2bf(tile[tx][i]);
    }
}

// ---------------- K3: build wst [304,1504] bf16 from convW|W0 stacked -------
__global__ void k_tws(const int* __restrict__ flag, const void* __restrict__ convW,
                      const void* __restrict__ W0, ushortT* __restrict__ wst) {
    int isb = flag[0];
    __shared__ float tile[32][33];
    int k0 = blockIdx.x * 32, d0 = blockIdx.y * 32;
    int tx = threadIdx.x & 31, ty = threadIdx.x >> 5;
    for (int i = ty; i < 32; i += 8) {
        int kp = k0 + i, d = d0 + tx;
        float v = 0.f;
        if (d < D && kp < 1500)
            v = (kp < 1200) ? ldf(convW, (size_t)kp * D + d, isb)
                            : ldf(W0, (size_t)(kp - 1200) * D + d, isb);
        tile[i][tx] = v;
    }
    __syncthreads();
    for (int i = ty; i < 32; i += 8) {
        int d = d0 + i;
        if (d < DPAD) wst[(size_t)d * KY + k0 + tx] = f2bf(tile[tx][i]);
    }
}

// ---------------- K4: build yb [128,1504] bf16 (graph-weighted row sums) ----
__global__ void k_yb(const ushortT* __restrict__ gxb, const int* __restrict__ ei,
                     const int* __restrict__ et, ushortT* __restrict__ yb) {
    int s = blockIdx.x;
    int t = threadIdx.x;  // 320
    __shared__ int se[E], de[E], te[E];
    __shared__ float disv[R][N];
    if (t < E) {
        se[t] = ei[(size_t)s * 2 * E + t];
        de[t] = ei[(size_t)s * 2 * E + E + t];
        te[t] = et[(size_t)s * E + t];
    }
    __syncthreads();
    if (t < R * N) {
        int r = t >> 5, n = t & 31;
        float c = 1.f;
        for (int e = 0; e < E; ++e) c += (te[e] == r && de[e] == n) ? 1.f : 0.f;
        disv[r][n] = rsqrtf(c);
    }
    __syncthreads();
    if (t < D) {
        const ushortT* g = gxb + (size_t)s * ND;
        float g0 = bf2f(g[t]);
        float yy[R];
#pragma unroll
        for (int r = 0; r < R; ++r) yy[r] = g0 * disv[r][0] * disv[r][0];
        for (int e = 0; e < E; ++e) {
            if (de[e] == 0) {
                int r = te[e];
                yy[r] += disv[r][se[e]] * disv[r][0] * bf2f(g[(size_t)se[e] * D + t]);
            }
        }
#pragma unroll
        for (int r = 0; r < R; ++r) yb[(size_t)s * KY + r * D + t] = f2bf(yy[r]);
        yb[(size_t)s * KY + 4 * D + t] = g[t];  // gx0 slot for W0
    }
    if (t < 4) yb[(size_t)s * KY + 1500 + t] = 0;
}

// ---------------- K5: GEMM partial over K-range (z-split) -------------------
__global__ __launch_bounds__(256) void k_gemm(const ushortT* __restrict__ A, int lda,
                                              const ushortT* __restrict__ Bt, int ldb,
                                              float* __restrict__ C, int ldc, int ncols,
                                              int kchunks, int per) {
    int wave = threadIdx.x >> 6, lane = threadIdx.x & 63;
    int col = lane & 15, quad = lane >> 4;
    int m0 = blockIdx.x * 16, n0 = blockIdx.y * 16;
    int z = blockIdx.z;
    int kbeg = z * per;
    int kend = kbeg + per;
    if (kend > kchunks) kend = kchunks;
    floatx4 acc = {0.f, 0.f, 0.f, 0.f};
    const ushortT* ap = A + (size_t)(m0 + col) * lda + quad * 8;
    const ushortT* bp = Bt + (size_t)(n0 + col) * ldb + quad * 8;
    for (int kc = kbeg + wave; kc < kend; kc += 4) {
        short8 a = *(const short8*)(ap + kc * 32);
        short8 b = *(const short8*)(bp + kc * 32);
        acc = __builtin_amdgcn_mfma_f32_16x16x32_bf16(a, b, acc, 0, 0, 0);
    }
    __shared__ float red[4][64][4];
#pragma unroll
    for (int i = 0; i < 4; ++i) red[wave][lane][i] = acc[i];
    __syncthreads();
    if (wave == 0) {
#pragma unroll
        for (int i = 0; i < 4; ++i) {
            float v = red[0][lane][i] + red[1][lane][i] + red[2][lane][i] + red[3][lane][i];
            int m = m0 + quad * 4 + i;
            int n = n0 + col;
            if (n < ncols) C[(size_t)z * S * ldc + (size_t)m * ldc + n] = v;
        }
    }
}

// ---------------- K5b: sum nz partials --------------------------------------
__global__ void k_red(const float* __restrict__ part, float* __restrict__ out, int n, int nz) {
    int i = blockIdx.x * 256 + threadIdx.x;
    if (i < n) {
        float v = 0.f;
        for (int z = 0; z < nz; ++z) v += part[(size_t)z * n + i];
        out[i] = v;
    }
}

// ---------------- K6: sequential scan, readlane matvec ----------------------
// 1024 thr = 16 waves pinned at 4 waves/EU (budget 128 VGPR). Wave w owns
// k-slice [w*19, w*19+19); lane covers 5 d's (d = 64p+lane). ug[5][19] = 95
// fp32 regs. Round-4 lesson: the round-3/4 spill (VGPR=108) was the unroller
// bailing on the 190-element branchy init -> dynamic indexing -> scratch.
// Fix: isb branch hoisted OUT of the init loops + array small enough that
// full unroll is trivial.
__global__ __attribute__((amdgpu_flat_work_group_size(1024, 1024), amdgpu_waves_per_eu(4, 4))) void
k_scan(const int* __restrict__ flag, const float* __restrict__ a, const float* __restrict__ P0,
       const void* __restrict__ Ug, ushortT* __restrict__ x1p) {
    int isb = flag[0];
    int t = threadIdx.x;
    int w = t >> 6, lane = t & 63;  // w 0..15
    float ug[5][19];
    if (isb) {
        const ushortT* U = (const ushortT*)Ug;
#pragma unroll
        for (int p = 0; p < 5; ++p) {
            int dd = 64 * p + lane;
            bool dok = dd < D;
#pragma unroll
            for (int j = 0; j < 19; ++j) {
                int k = w * 19 + j;
                ug[p][j] = (dok && k < D) ? bf2f(U[k * D + dd]) : 0.f;
            }
        }
    } else {
        const float* U = (const float*)Ug;
#pragma unroll
        for (int p = 0; p < 5; ++p) {
            int dd = 64 * p + lane;
            bool dok = dd < D;
#pragma unroll
            for (int j = 0; j < 19; ++j) {
                int k = w * 19 + j;
                ug[p][j] = (dok && k < D) ? U[k * D + dd] : 0.f;
            }
        }
    }
    __shared__ float msh[352];
    __shared__ float part[16][320];
    for (int i = t; i < 352; i += 1024) msh[i] = 0.f;
    float mreg = 0.f;  // m value at index t (t<300), persists across steps
    __syncthreads();
    for (int s = 0; s < S; ++s) {
        float av = 0.f, pv = 0.f;
        if (t < D) {
            av = a[s * D + t];
            pv = P0[s * D + t];
        }
        float chunk = msh[w * 19 + lane];  // max 15*19+63=348 < 352 (zero pad)
        float acc0 = 0.f, acc1 = 0.f, acc2 = 0.f, acc3 = 0.f, acc4 = 0.f;
#pragma unroll
        for (int j = 0; j < 19; ++j) {
            float sm = rdlane(chunk, j);
            acc0 = fmaf(sm, ug[0][j], acc0);
            acc1 = fmaf(sm, ug[1][j], acc1);
            acc2 = fmaf(sm, ug[2][j], acc2);
            acc3 = fmaf(sm, ug[3][j], acc3);
            acc4 = fmaf(sm, ug[4][j], acc4);
        }
        part[w][lane] = acc0;
        part[w][64 + lane] = acc1;
        part[w][128 + lane] = acc2;
        part[w][192 + lane] = acc3;
        part[w][256 + lane] = acc4;
        __syncthreads();
        if (t < 320) {
            float pr = 0.f;
#pragma unroll
            for (int w2 = 0; w2 < 16; ++w2) pr += part[w2][t];
            if (t < D) {
                float pre = av + pr;
                float u = 1.f / (1.f + __expf(-pre));
                float nm = u * pv + (1.f - u) * mreg;
                mreg = nm;
                msh[t] = nm;
                float x = nm > 0.f ? nm : 0.01f * nm;
                x1p[(size_t)s * DP + t] = f2bf(x);
            } else {
                x1p[(size_t)s * DP + t] = 0;
            }
        }
        __syncthreads();
    }
}

// ---------------- K7: logits = x1 @ lin_w^T + b via MFMA --------------------
__global__ __launch_bounds__(256) void k_logits(const int* __restrict__ flag,
                                                const ushortT* __restrict__ x1p,
                                                const void* __restrict__ lw,
                                                const void* __restrict__ lb,
                                                void* __restrict__ out) {
    int isb = flag[0];
    int wave = threadIdx.x >> 6, lane = threadIdx.x & 63;
    int col = lane & 15, quad = lane >> 4;
    int v = blockIdx.x * 64 + wave * 16 + col;
    int vv = v < V ? v : V - 1;
    floatx4 acc[8];
#pragma unroll
    for (int i = 0; i < 8; ++i) acc[i] = (floatx4){0.f, 0.f, 0.f, 0.f};
#pragma unroll
    for (int kc = 0; kc < 9; ++kc) {
        int k0 = kc * 32 + quad * 8;
        short8 b;
        if (isb) {
            const ushortT* bp = (const ushortT*)lw + (size_t)vv * D + k0;  // 8B aligned
            short4v lo = *(const short4v*)bp;
            short4v hi = *(const short4v*)(bp + 4);
            b = (short8){lo[0], lo[1], lo[2], lo[3], hi[0], hi[1], hi[2], hi[3]};
        } else {
            const float* bp = (const float*)lw + (size_t)vv * D + k0;  // 16B aligned
            floatx4 f0 = *(const floatx4*)bp;
            floatx4 f1 = *(const floatx4*)(bp + 4);
            b = (short8){(short)f2bf(f0[0]), (short)f2bf(f0[1]), (short)f2bf(f0[2]),
                         (short)f2bf(f0[3]), (short)f2bf(f1[0]), (short)f2bf(f1[1]),
                         (short)f2bf(f1[2]), (short)f2bf(f1[3])};
        }
#pragma unroll
        for (int st = 0; st < 8; ++st) {
            short8 aa = *(const short8*)(x1p + (size_t)(st * 16 + col) * DP + k0);
            acc[st] = __builtin_amdgcn_mfma_f32_16x16x32_bf16(aa, b, acc[st], 0, 0, 0);
        }
    }
    {  // tail chunk k=288..319 (lin_w valid only k<300; x1p zero-padded)
        int k0 = 288 + quad * 8;
        short8 b;
#pragma unroll
        for (int j = 0; j < 8; ++j) {
            int k = k0 + j;
            ushortT bv = 0;
            if (k < D)
                bv = isb ? ((const ushortT*)lw)[(size_t)vv * D + k]
                         : f2bf(((const float*)lw)[(size_t)vv * D + k]);
            b[j] = (short)bv;
        }
#pragma unroll
        for (int st = 0; st < 8; ++st) {
            short8 aa = *(const short8*)(x1p + (size_t)(st * 16 + col) * DP + k0);
            acc[st] = __builtin_amdgcn_mfma_f32_16x16x32_bf16(aa, b, acc[st], 0, 0, 0);
        }
    }
    if (v < V) {
        float bias = ldf(lb, v, isb);
#pragma unroll
        for (int st = 0; st < 8; ++st) {
#pragma unroll
            for (int i = 0; i < 4; ++i) {
                int s = st * 16 + quad * 4 + i;
                float val = acc[st][i] + bias;
                if (isb)
                    ((ushortT*)out)[(size_t)s * V + v] = f2bf(val);
                else
                    ((float*)out)[(size_t)s * V + v] = val;
            }
        }
    }
}

// ---------------- K8: fused logsumexp + in-place normalize + senses tail ----
// One block per row s. Vectorized 16B loads (8 bf16 / 4 fp32 per load).
__global__ __launch_bounds__(512) void k_norm(const int* __restrict__ flag,
                                              void* __restrict__ out) {
    int isb = flag[0];
    int s = blockIdx.x;
    int t = threadIdx.x;
    __shared__ float red[512];
    // zero the senses tail (independent region) from block 0
    if (s == 0 && t < S) {
        if (isb)
            ((ushortT*)out)[(size_t)S * V + t] = 0;
        else
            ((float*)out)[(size_t)S * V + t] = 0.f;
    }
    float mx = -1e30f;
    if (isb) {
        const uint4* row = (const uint4*)((const ushortT*)out + (size_t)s * V);  // 6250 vecs
        for (int i = t; i < 6250; i += 512) {
            uint4 q = row[i];
            mx = fmaxf(mx, fmaxf(fmaxf(bfbits_lo(q.x), bfbits_hi(q.x)),
                                 fmaxf(bfbits_lo(q.y), bfbits_hi(q.y))));
            mx = fmaxf(mx, fmaxf(fmaxf(bfbits_lo(q.z), bfbits_hi(q.z)),
                                 fmaxf(bfbits_lo(q.w), bfbits_hi(q.w))));
        }
    } else {
        const floatx4* row = (const floatx4*)((const float*)out + (size_t)s * V);  // 12500 vecs
        for (int i = t; i < 12500; i += 512) {
            floatx4 q = row[i];
            mx = fmaxf(mx, fmaxf(fmaxf(q[0], q[1]), fmaxf(q[2], q[3])));
        }
    }
    red[t] = mx;
    __syncthreads();
    for (int o = 256; o > 0; o >>= 1) {
        if (t < o) red[t] = fmaxf(red[t], red[t + o]);
        __syncthreads();
    }
    float M = red[0];
    __syncthreads();
    float sm = 0.f;
    if (isb) {
        const uint4* row = (const uint4*)((const ushortT*)out + (size_t)s * V);
        for (int i = t; i < 6250; i += 512) {
            uint4 q = row[i];
            sm += __expf(bfbits_lo(q.x) - M) + __expf(bfbits_hi(q.x) - M) +
                  __expf(bfbits_lo(q.y) - M) + __expf(bfbits_hi(q.y) - M) +
                  __expf(bfbits_lo(q.z) - M) + __expf(bfbits_hi(q.z) - M) +
                  __expf(bfbits_lo(q.w) - M) + __expf(bfbits_hi(q.w) - M);
        }
    } else {
        const floatx4* row = (const floatx4*)((const float*)out + (size_t)s * V);
        for (int i = t; i < 12500; i += 512) {
            floatx4 q = row[i];
            sm += __expf(q[0] - M) + __expf(q[1] - M) + __expf(q[2] - M) + __expf(q[3] - M);
        }
    }
    red[t] = sm;
    __syncthreads();
    for (int o = 256; o > 0; o >>= 1) {
        if (t < o) red[t] += red[t + o];
        __syncthreads();
    }
    float lse = M + __logf(red[0]);
    if (isb) {
        uint4* row = (uint4*)((ushortT*)out + (size_t)s * V);
        for (int i = t; i < 6250; i += 512) {
            uint4 q = row[i];
            uint4 o;
            o.x = (unsigned)f2bf(bfbits_lo(q.x) - lse) |
                  ((unsigned)f2bf(bfbits_hi(q.x) - lse) << 16);
            o.y = (unsigned)f2bf(bfbits_lo(q.y) - lse) |
                  ((unsigned)f2bf(bfbits_hi(q.y) - lse) << 16);
            o.z = (unsigned)f2bf(bfbits_lo(q.z) - lse) |
                  ((unsigned)f2bf(bfbits_hi(q.z) - lse) << 16);
            o.w = (unsigned)f2bf(bfbits_lo(q.w) - lse) |
                  ((unsigned)f2bf(bfbits_hi(q.w) - lse) << 16);
            row[i] = o;
        }
    } else {
        floatx4* row = (floatx4*)((float*)out + (size_t)s * V);
        for (int i = t; i < 12500; i += 512) {
            floatx4 q = row[i];
            q[0] -= lse;
            q[1] -= lse;
            q[2] -= lse;
            q[3] -= lse;
            row[i] = q;
        }
    }
}

// ---------------- workspace layout (bytes, all 256-aligned) -----------------
#define OFF_FLAG 0
#define OFF_GXB 256
#define OFF_WGT 2457856
#define OFF_WST 8294656
#define OFF_YB 9209088
#define OFF_A 9594112
#define OFF_P0 9747712
#define OFF_X1P 9901312
#define OFF_STATS 9983232
#define OFF_PART 9983744  // optional z-split partial buffers (needs bigger ws)
#define PART_A_BYTES (4 * S * D * 4)
#define PART_P_BYTES (2 * S * D * 4)

extern "C" void kernel_launch(void* const* d_in, const int* in_sizes, int n_in, void* d_out,
                              int out_size, void* d_ws, size_t ws_size, hipStream_t stream) {
    const int* xi = (const int*)d_in[0];
    const int* ei = (const int*)d_in[1];
    const int* et = (const int*)d_in[2];
    const void* X = d_in[3];
    const void* convW = d_in[4];
    const void* W0 = d_in[5];
    const void* Wg = d_in[6];
    const void* Ug = d_in[7];
    const void* lw = d_in[8];
    const void* lb = d_in[9];
    char* ws = (char*)d_ws;

    int* flag = (int*)(ws + OFF_FLAG);
    ushortT* gxb = (ushortT*)(ws + OFF_GXB);
    ushortT* wgt = (ushortT*)(ws + OFF_WGT);
    ushortT* wst = (ushortT*)(ws + OFF_WST);
    ushortT* yb = (ushortT*)(ws + OFF_YB);
    float* a = (float*)(ws + OFF_A);
    float* P0 = (float*)(ws + OFF_P0);
    ushortT* x1p = (ushortT*)(ws + OFF_X1P);

    // z-split K only if workspace is big enough for partial buffers
    bool split = ws_size >= (size_t)(OFF_PART + PART_A_BYTES + PART_P_BYTES);
    int nza = split ? 4 : 1;
    int nzp = split ? 2 : 1;
    float* apart = split ? (float*)(ws + OFF_PART) : a;
    float* ppart = split ? (float*)(ws + OFF_PART + PART_A_BYTES) : P0;
    int pera = (ND / 32 + nza - 1) / nza;
    int perp = (KY / 32 + nzp - 1) / nzp;

    hipLaunchKernelGGL(k_detect, dim3(1), dim3(256), 0, stream, X, flag);
    hipLaunchKernelGGL(k_gatherb, dim3(S * N), dim3(DP), 0, stream, flag, xi, X, gxb);
    hipLaunchKernelGGL(k_twg, dim3(ND / 32, 10), dim3(256), 0, stream, flag, Wg, wgt);
    hipLaunchKernelGGL(k_tws, dim3(KY / 32, 10), dim3(256), 0, stream, flag, convW, W0, wst);
    hipLaunchKernelGGL(k_yb, dim3(S), dim3(DP), 0, stream, gxb, ei, et, yb);
    hipLaunchKernelGGL(k_gemm, dim3(S / 16, 19, nza), dim3(256), 0, stream, gxb, ND, wgt, ND,
                       apart, D, D, ND / 32, pera);
    if (split)
        hipLaunchKernelGGL(k_red, dim3((S * D + 255) / 256), dim3(256), 0, stream, apart, a,
                           S * D, nza);
    hipLaunchKernelGGL(k_gemm, dim3(S / 16, 19, nzp), dim3(256), 0, stream, yb, KY, wst, KY,
                       ppart, D, D, KY / 32, perp);
    if (split)
        hipLaunchKernelGGL(k_red, dim3((S * D + 255) / 256), dim3(256), 0, stream, ppart, P0,
                           S * D, nzp);
    hipLaunchKernelGGL(k_scan, dim3(1), dim3(1024), 0, stream, flag, a, P0, Ug, x1p);
    hipLaunchKernelGGL(k_logits, dim3(VP / 64), dim3(256), 0, stream, flag, x1p, lw, lb, d_out);
    hipLaunchKernelGGL(k_norm, dim3(S), dim3(512), 0, stream, flag, d_out);
}

// Round 6
// 462.698 us; speedup vs baseline: 1.1707x; 1.0034x over previous
//
#include <hip/hip_runtime.h>

#define S 128
#define N 32
#define D 300
#define DP 320
#define E 64
#define R 4
#define V 50000
#define VP 50048
#define ND 9600
#define KY 1504   // stacked K for P0 GEMM: 4*300 conv + 300 W0 + 4 pad
#define DPAD 304  // padded N rows for Bt matrices

typedef unsigned short ushortT;
typedef __attribute__((ext_vector_type(8))) short short8;
typedef __attribute__((ext_vector_type(4))) short short4v;
typedef __attribute__((ext_vector_type(4))) float floatx4;
typedef __attribute__((ext_vector_type(19))) float floatx19;  // SSA vector: never memory

__device__ inline float bf2f(ushortT h) {
    unsigned u = ((unsigned)h) << 16;
    float f;
    __builtin_memcpy(&f, &u, 4);
    return f;
}

__device__ inline float bfbits_lo(unsigned u) {
    unsigned b = u << 16;
    float f;
    __builtin_memcpy(&f, &b, 4);
    return f;
}

__device__ inline float bfbits_hi(unsigned u) {
    unsigned b = u & 0xffff0000u;
    float f;
    __builtin_memcpy(&f, &b, 4);
    return f;
}

__device__ inline ushortT f2bf(float f) {
    unsigned u;
    __builtin_memcpy(&u, &f, 4);
    unsigned r = (u + 0x7fffu + ((u >> 16) & 1u)) >> 16;
    return (ushortT)r;
}

__device__ inline float ldf(const void* p, size_t i, int isb) {
    return isb ? bf2f(((const ushortT*)p)[i]) : ((const float*)p)[i];
}

__device__ inline float rdlane(float v, int lane) {
    int iv;
    __builtin_memcpy(&iv, &v, 4);
    int r = __builtin_amdgcn_readlane(iv, lane);
    float f;
    __builtin_memcpy(&f, &r, 4);
    return f;
}

// ---------------- K_detect: decide input dtype ------------------------------
__global__ void k_detect(const void* X, int* flag) {
    __shared__ int bad;
    if (threadIdx.x == 0) bad = 0;
    __syncthreads();
    const ushortT* p = (const ushortT*)X;
    int b = 0;
    for (int i = threadIdx.x; i < 4096; i += 256) {
        float v = bf2f(p[i]);
        if (!(v > -2.f && v < 2.f)) b = 1;  // catches NaN/Inf too
    }
    if (b) atomicOr(&bad, 1);
    __syncthreads();
    if (threadIdx.x == 0) flag[0] = bad ? 0 : 1;
}

// ---------------- K1: gather gxb[sn][d] = bf16(X[idx[sn]][d]) ---------------
__global__ void k_gatherb(const int* __restrict__ flag, const int* __restrict__ xi,
                          const void* __restrict__ X, ushortT* __restrict__ gxb) {
    int isb = flag[0];
    int sn = blockIdx.x;
    int d = threadIdx.x;
    if (d < D) {
        int node = xi[sn];
        ushortT v = isb ? ((const ushortT*)X)[(size_t)node * D + d]
                        : f2bf(((const float*)X)[(size_t)node * D + d]);
        gxb[(size_t)sn * D + d] = v;
    }
}

// ---------------- K2: transpose Wg [9600,300] -> wgt [304,9600] bf16 --------
__global__ void k_twg(const int* __restrict__ flag, const void* __restrict__ Wg,
                      ushortT* __restrict__ wgt) {
    int isb = flag[0];
    __shared__ float tile[32][33];
    int k0 = blockIdx.x * 32, d0 = blockIdx.y * 32;
    int tx = threadIdx.x & 31, ty = threadIdx.x >> 5;  // 32x8
    for (int i = ty; i < 32; i += 8) {
        int d = d0 + tx;
        tile[i][tx] = (d < D) ? ldf(Wg, (size_t)(k0 + i) * D + d, isb) : 0.f;
    }
    __syncthreads();
    for (int i = ty; i < 32; i += 8) {
        int d = d0 + i;
        if (d < DPAD) wgt[(size_t)d * ND + k0 + tx] = f2bf(tile[tx][i]);
    }
}

// ---------------- K3: build wst [304,1504] bf16 from convW|W0 stacked -------
__global__ void k_tws(const int* __restrict__ flag, const void* __restrict__ convW,
                      const void* __restrict__ W0, ushortT* __restrict__ wst) {
    int isb = flag[0];
    __shared__ float tile[32][33];
    int k0 = blockIdx.x * 32, d0 = blockIdx.y * 32;
    int tx = threadIdx.x & 31, ty = threadIdx.x >> 5;
    for (int i = ty; i < 32; i += 8) {
        int kp = k0 + i, d = d0 + tx;
        float v = 0.f;
        if (d < D && kp < 1500)
            v = (kp < 1200) ? ldf(convW, (size_t)kp * D + d, isb)
                            : ldf(W0, (size_t)(kp - 1200) * D + d, isb);
        tile[i][tx] = v;
    }
    __syncthreads();
    for (int i = ty; i < 32; i += 8) {
        int d = d0 + i;
        if (d < DPAD) wst[(size_t)d * KY + k0 + tx] = f2bf(tile[tx][i]);
    }
}

// ---------------- K4: build yb [128,1504] bf16 (graph-weighted row sums) ----
__global__ void k_yb(const ushortT* __restrict__ gxb, const int* __restrict__ ei,
                     const int* __restrict__ et, ushortT* __restrict__ yb) {
    int s = blockIdx.x;
    int t = threadIdx.x;  // 320
    __shared__ int se[E], de[E], te[E];
    __shared__ float disv[R][N];
    if (t < E) {
        se[t] = ei[(size_t)s * 2 * E + t];
        de[t] = ei[(size_t)s * 2 * E + E + t];
        te[t] = et[(size_t)s * E + t];
    }
    __syncthreads();
    if (t < R * N) {
        int r = t >> 5, n = t & 31;
        float c = 1.f;
        for (int e = 0; e < E; ++e) c += (te[e] == r && de[e] == n) ? 1.f : 0.f;
        disv[r][n] = rsqrtf(c);
    }
    __syncthreads();
    if (t < D) {
        const ushortT* g = gxb + (size_t)s * ND;
        float g0 = bf2f(g[t]);
        float yy[R];
#pragma unroll
        for (int r = 0; r < R; ++r) yy[r] = g0 * disv[r][0] * disv[r][0];
        for (int e = 0; e < E; ++e) {
            if (de[e] == 0) {
                int r = te[e];
                yy[r] += disv[r][se[e]] * disv[r][0] * bf2f(g[(size_t)se[e] * D + t]);
            }
        }
#pragma unroll
        for (int r = 0; r < R; ++r) yb[(size_t)s * KY + r * D + t] = f2bf(yy[r]);
        yb[(size_t)s * KY + 4 * D + t] = g[t];  // gx0 slot for W0
    }
    if (t < 4) yb[(size_t)s * KY + 1500 + t] = 0;
}

// ---------------- K5: GEMM partial over K-range (z-split) -------------------
__global__ __launch_bounds__(256) void k_gemm(const ushortT* __restrict__ A, int lda,
                                              const ushortT* __restrict__ Bt, int ldb,
                                              float* __restrict__ C, int ldc, int ncols,
                                              int kchunks, int per) {
    int wave = threadIdx.x >> 6, lane = threadIdx.x & 63;
    int col = lane & 15, quad = lane >> 4;
    int m0 = blockIdx.x * 16, n0 = blockIdx.y * 16;
    int z = blockIdx.z;
    int kbeg = z * per;
    int kend = kbeg + per;
    if (kend > kchunks) kend = kchunks;
    floatx4 acc = {0.f, 0.f, 0.f, 0.f};
    const ushortT* ap = A + (size_t)(m0 + col) * lda + quad * 8;
    const ushortT* bp = Bt + (size_t)(n0 + col) * ldb + quad * 8;
    for (int kc = kbeg + wave; kc < kend; kc += 4) {
        short8 a = *(const short8*)(ap + kc * 32);
        short8 b = *(const short8*)(bp + kc * 32);
        acc = __builtin_amdgcn_mfma_f32_16x16x32_bf16(a, b, acc, 0, 0, 0);
    }
    __shared__ float red[4][64][4];
#pragma unroll
    for (int i = 0; i < 4; ++i) red[wave][lane][i] = acc[i];
    __syncthreads();
    if (wave == 0) {
#pragma unroll
        for (int i = 0; i < 4; ++i) {
            float v = red[0][lane][i] + red[1][lane][i] + red[2][lane][i] + red[3][lane][i];
            int m = m0 + quad * 4 + i;
            int n = n0 + col;
            if (n < ncols) C[(size_t)z * S * ldc + (size_t)m * ldc + n] = v;
        }
    }
}

// ---------------- K5b: sum nz partials --------------------------------------
__global__ void k_red(const float* __restrict__ part, float* __restrict__ out, int n, int nz) {
    int i = blockIdx.x * 256 + threadIdx.x;
    if (i < n) {
        float v = 0.f;
        for (int z = 0; z < nz; ++z) v += part[(size_t)z * n + i];
        out[i] = v;
    }
}

// ---------------- K6: sequential scan, Ug in SSA vector registers -----------
// Rounds 3-5 lesson: an indexed per-thread ARRAY (ug[5][19]) is never
// SROA-promoted here (VGPR_Count 108/108/60 < array size) -> scratch reload
// every step. Fix: ext_vector_type values are first-class SSA (never memory);
// constant-index extract/insert = direct register refs. 512 thr = 8 waves,
// waves_per_eu(2,2) -> 256-VGPR budget; need ~190+25.
// Wave w owns k-slice [w*38, w*38+38); lane covers d = 64p+lane, p=0..4.
__global__ __attribute__((amdgpu_flat_work_group_size(512, 512), amdgpu_waves_per_eu(2, 2))) void
k_scan(const int* __restrict__ flag, const float* __restrict__ a, const float* __restrict__ P0,
       const void* __restrict__ Ug, ushortT* __restrict__ x1p) {
    int isb = flag[0];
    int t = threadIdx.x;
    int w = t >> 6, lane = t & 63;  // w 0..7
    int kbase = w * 38;
    int d4 = 256 + lane;
    bool d4ok = d4 < D;  // only the p=4 slice can exceed D
    // k-masks: kbase+j (j<19) <= 7*38+18 = 284 < 300 always ok;
    //          kbase+19+j  <= 303 -> mask needed.
    floatx19 A0, A1, A2, A3, A4, B0, B1, B2, B3, B4;
    if (isb) {
        const ushortT* U = (const ushortT*)Ug;
#pragma unroll
        for (int j = 0; j < 19; ++j) {
            int k1 = kbase + j, k2 = k1 + 19;
            bool k2ok = k2 < D;
            A0[j] = bf2f(U[k1 * D + lane]);
            A1[j] = bf2f(U[k1 * D + 64 + lane]);
            A2[j] = bf2f(U[k1 * D + 128 + lane]);
            A3[j] = bf2f(U[k1 * D + 192 + lane]);
            A4[j] = d4ok ? bf2f(U[k1 * D + d4]) : 0.f;
            B0[j] = k2ok ? bf2f(U[k2 * D + lane]) : 0.f;
            B1[j] = k2ok ? bf2f(U[k2 * D + 64 + lane]) : 0.f;
            B2[j] = k2ok ? bf2f(U[k2 * D + 128 + lane]) : 0.f;
            B3[j] = k2ok ? bf2f(U[k2 * D + 192 + lane]) : 0.f;
            B4[j] = (k2ok && d4ok) ? bf2f(U[k2 * D + d4]) : 0.f;
        }
    } else {
        const float* U = (const float*)Ug;
#pragma unroll
        for (int j = 0; j < 19; ++j) {
            int k1 = kbase + j, k2 = k1 + 19;
            bool k2ok = k2 < D;
            A0[j] = U[k1 * D + lane];
            A1[j] = U[k1 * D + 64 + lane];
            A2[j] = U[k1 * D + 128 + lane];
            A3[j] = U[k1 * D + 192 + lane];
            A4[j] = d4ok ? U[k1 * D + d4] : 0.f;
            B0[j] = k2ok ? U[k2 * D + lane] : 0.f;
            B1[j] = k2ok ? U[k2 * D + 64 + lane] : 0.f;
            B2[j] = k2ok ? U[k2 * D + 128 + lane] : 0.f;
            B3[j] = k2ok ? U[k2 * D + 192 + lane] : 0.f;
            B4[j] = (k2ok && d4ok) ? U[k2 * D + d4] : 0.f;
        }
    }
    __shared__ float msh[336];
    __shared__ float part[8][320];
    for (int i = t; i < 336; i += 512) msh[i] = 0.f;
    float mreg = 0.f;  // m value at index t (t<300), persists across steps
    __syncthreads();
    for (int s = 0; s < S; ++s) {
        float av = 0.f, pv = 0.f;
        if (t < D) {
            av = a[s * D + t];
            pv = P0[s * D + t];
        }
        float chunk = msh[kbase + lane];  // max 7*38+63=329 < 336 (zero pad)
        float acc0 = 0.f, acc1 = 0.f, acc2 = 0.f, acc3 = 0.f, acc4 = 0.f;
#pragma unroll
        for (int j = 0; j < 19; ++j) {
            float sm = rdlane(chunk, j);
            acc0 = fmaf(sm, A0[j], acc0);
            acc1 = fmaf(sm, A1[j], acc1);
            acc2 = fmaf(sm, A2[j], acc2);
            acc3 = fmaf(sm, A3[j], acc3);
            acc4 = fmaf(sm, A4[j], acc4);
        }
#pragma unroll
        for (int j = 0; j < 19; ++j) {
            float sm = rdlane(chunk, 19 + j);
            acc0 = fmaf(sm, B0[j], acc0);
            acc1 = fmaf(sm, B1[j], acc1);
            acc2 = fmaf(sm, B2[j], acc2);
            acc3 = fmaf(sm, B3[j], acc3);
            acc4 = fmaf(sm, B4[j], acc4);
        }
        part[w][lane] = acc0;
        part[w][64 + lane] = acc1;
        part[w][128 + lane] = acc2;
        part[w][192 + lane] = acc3;
        part[w][256 + lane] = acc4;
        __syncthreads();
        if (t < 320) {
            float pr = 0.f;
#pragma unroll
            for (int w2 = 0; w2 < 8; ++w2) pr += part[w2][t];
            if (t < D) {
                float pre = av + pr;
                float u = 1.f / (1.f + __expf(-pre));
                float nm = u * pv + (1.f - u) * mreg;
                mreg = nm;
                msh[t] = nm;
                float x = nm > 0.f ? nm : 0.01f * nm;
                x1p[(size_t)s * DP + t] = f2bf(x);
            } else {
                x1p[(size_t)s * DP + t] = 0;
            }
        }
        __syncthreads();
    }
}

// ---------------- K7: logits = x1 @ lin_w^T + b via MFMA --------------------
__global__ __launch_bounds__(256) void k_logits(const int* __restrict__ flag,
                                                const ushortT* __restrict__ x1p,
                                                const void* __restrict__ lw,
                                                const void* __restrict__ lb,
                                                void* __restrict__ out) {
    int isb = flag[0];
    int wave = threadIdx.x >> 6, lane = threadIdx.x & 63;
    int col = lane & 15, quad = lane >> 4;
    int v = blockIdx.x * 64 + wave * 16 + col;
    int vv = v < V ? v : V - 1;
    floatx4 acc[8];
#pragma unroll
    for (int i = 0; i < 8; ++i) acc[i] = (floatx4){0.f, 0.f, 0.f, 0.f};
#pragma unroll
    for (int kc = 0; kc < 9; ++kc) {
        int k0 = kc * 32 + quad * 8;
        short8 b;
        if (isb) {
            const ushortT* bp = (const ushortT*)lw + (size_t)vv * D + k0;  // 8B aligned
            short4v lo = *(const short4v*)bp;
            short4v hi = *(const short4v*)(bp + 4);
            b = (short8){lo[0], lo[1], lo[2], lo[3], hi[0], hi[1], hi[2], hi[3]};
        } else {
            const float* bp = (const float*)lw + (size_t)vv * D + k0;  // 16B aligned
            floatx4 f0 = *(const floatx4*)bp;
            floatx4 f1 = *(const floatx4*)(bp + 4);
            b = (short8){(short)f2bf(f0[0]), (short)f2bf(f0[1]), (short)f2bf(f0[2]),
                         (short)f2bf(f0[3]), (short)f2bf(f1[0]), (short)f2bf(f1[1]),
                         (short)f2bf(f1[2]), (short)f2bf(f1[3])};
        }
#pragma unroll
        for (int st = 0; st < 8; ++st) {
            short8 aa = *(const short8*)(x1p + (size_t)(st * 16 + col) * DP + k0);
            acc[st] = __builtin_amdgcn_mfma_f32_16x16x32_bf16(aa, b, acc[st], 0, 0, 0);
        }
    }
    {  // tail chunk k=288..319 (lin_w valid only k<300; x1p zero-padded)
        int k0 = 288 + quad * 8;
        short8 b;
#pragma unroll
        for (int j = 0; j < 8; ++j) {
            int k = k0 + j;
            ushortT bv = 0;
            if (k < D)
                bv = isb ? ((const ushortT*)lw)[(size_t)vv * D + k]
                         : f2bf(((const float*)lw)[(size_t)vv * D + k]);
            b[j] = (short)bv;
        }
#pragma unroll
        for (int st = 0; st < 8; ++st) {
            short8 aa = *(const short8*)(x1p + (size_t)(st * 16 + col) * DP + k0);
            acc[st] = __builtin_amdgcn_mfma_f32_16x16x32_bf16(aa, b, acc[st], 0, 0, 0);
        }
    }
    if (v < V) {
        float bias = ldf(lb, v, isb);
#pragma unroll
        for (int st = 0; st < 8; ++st) {
#pragma unroll
            for (int i = 0; i < 4; ++i) {
                int s = st * 16 + quad * 4 + i;
                float val = acc[st][i] + bias;
                if (isb)
                    ((ushortT*)out)[(size_t)s * V + v] = f2bf(val);
                else
                    ((float*)out)[(size_t)s * V + v] = val;
            }
        }
    }
}

// ---------------- K8: fused logsumexp + in-place normalize + senses tail ----
__global__ __launch_bounds__(512) void k_norm(const int* __restrict__ flag,
                                              void* __restrict__ out) {
    int isb = flag[0];
    int s = blockIdx.x;
    int t = threadIdx.x;
    __shared__ float red[512];
    if (s == 0 && t < S) {
        if (isb)
            ((ushortT*)out)[(size_t)S * V + t] = 0;
        else
            ((float*)out)[(size_t)S * V + t] = 0.f;
    }
    float mx = -1e30f;
    if (isb) {
        const uint4* row = (const uint4*)((const ushortT*)out + (size_t)s * V);  // 6250 vecs
        for (int i = t; i < 6250; i += 512) {
            uint4 q = row[i];
            mx = fmaxf(mx, fmaxf(fmaxf(bfbits_lo(q.x), bfbits_hi(q.x)),
                                 fmaxf(bfbits_lo(q.y), bfbits_hi(q.y))));
            mx = fmaxf(mx, fmaxf(fmaxf(bfbits_lo(q.z), bfbits_hi(q.z)),
                                 fmaxf(bfbits_lo(q.w), bfbits_hi(q.w))));
        }
    } else {
        const floatx4* row = (const floatx4*)((const float*)out + (size_t)s * V);  // 12500 vecs
        for (int i = t; i < 12500; i += 512) {
            floatx4 q = row[i];
            mx = fmaxf(mx, fmaxf(fmaxf(q[0], q[1]), fmaxf(q[2], q[3])));
        }
    }
    red[t] = mx;
    __syncthreads();
    for (int o = 256; o > 0; o >>= 1) {
        if (t < o) red[t] = fmaxf(red[t], red[t + o]);
        __syncthreads();
    }
    float M = red[0];
    __syncthreads();
    float sm = 0.f;
    if (isb) {
        const uint4* row = (const uint4*)((const ushortT*)out + (size_t)s * V);
        for (int i = t; i < 6250; i += 512) {
            uint4 q = row[i];
            sm += __expf(bfbits_lo(q.x) - M) + __expf(bfbits_hi(q.x) - M) +
                  __expf(bfbits_lo(q.y) - M) + __expf(bfbits_hi(q.y) - M) +
                  __expf(bfbits_lo(q.z) - M) + __expf(bfbits_hi(q.z) - M) +
                  __expf(bfbits_lo(q.w) - M) + __expf(bfbits_hi(q.w) - M);
        }
    } else {
        const floatx4* row = (const floatx4*)((const float*)out + (size_t)s * V);
        for (int i = t; i < 12500; i += 512) {
            floatx4 q = row[i];
            sm += __expf(q[0] - M) + __expf(q[1] - M) + __expf(q[2] - M) + __expf(q[3] - M);
        }
    }
    red[t] = sm;
    __syncthreads();
    for (int o = 256; o > 0; o >>= 1) {
        if (t < o) red[t] += red[t + o];
        __syncthreads();
    }
    float lse = M + __logf(red[0]);
    if (isb) {
        uint4* row = (uint4*)((ushortT*)out + (size_t)s * V);
        for (int i = t; i < 6250; i += 512) {
            uint4 q = row[i];
            uint4 o;
            o.x = (unsigned)f2bf(bfbits_lo(q.x) - lse) |
                  ((unsigned)f2bf(bfbits_hi(q.x) - lse) << 16);
            o.y = (unsigned)f2bf(bfbits_lo(q.y) - lse) |
                  ((unsigned)f2bf(bfbits_hi(q.y) - lse) << 16);
            o.z = (unsigned)f2bf(bfbits_lo(q.z) - lse) |
                  ((unsigned)f2bf(bfbits_hi(q.z) - lse) << 16);
            o.w = (unsigned)f2bf(bfbits_lo(q.w) - lse) |
                  ((unsigned)f2bf(bfbits_hi(q.w) - lse) << 16);
            row[i] = o;
        }
    } else {
        floatx4* row = (floatx4*)((float*)out + (size_t)s * V);
        for (int i = t; i < 12500; i += 512) {
            floatx4 q = row[i];
            q[0] -= lse;
            q[1] -= lse;
            q[2] -= lse;
            q[3] -= lse;
            row[i] = q;
        }
    }
}

// ---------------- workspace layout (bytes, all 256-aligned) -----------------
#define OFF_FLAG 0
#define OFF_GXB 256
#define OFF_WGT 2457856
#define OFF_WST 8294656
#define OFF_YB 9209088
#define OFF_A 9594112
#define OFF_P0 9747712
#define OFF_X1P 9901312
#define OFF_STATS 9983232
#define OFF_PART 9983744  // optional z-split partial buffers (needs bigger ws)
#define PART_A_BYTES (4 * S * D * 4)
#define PART_P_BYTES (2 * S * D * 4)

extern "C" void kernel_launch(void* const* d_in, const int* in_sizes, int n_in, void* d_out,
                              int out_size, void* d_ws, size_t ws_size, hipStream_t stream) {
    const int* xi = (const int*)d_in[0];
    const int* ei = (const int*)d_in[1];
    const int* et = (const int*)d_in[2];
    const void* X = d_in[3];
    const void* convW = d_in[4];
    const void* W0 = d_in[5];
    const void* Wg = d_in[6];
    const void* Ug = d_in[7];
    const void* lw = d_in[8];
    const void* lb = d_in[9];
    char* ws = (char*)d_ws;

    int* flag = (int*)(ws + OFF_FLAG);
    ushortT* gxb = (ushortT*)(ws + OFF_GXB);
    ushortT* wgt = (ushortT*)(ws + OFF_WGT);
    ushortT* wst = (ushortT*)(ws + OFF_WST);
    ushortT* yb = (ushortT*)(ws + OFF_YB);
    float* a = (float*)(ws + OFF_A);
    float* P0 = (float*)(ws + OFF_P0);
    ushortT* x1p = (ushortT*)(ws + OFF_X1P);

    // z-split K only if workspace is big enough for partial buffers
    bool split = ws_size >= (size_t)(OFF_PART + PART_A_BYTES + PART_P_BYTES);
    int nza = split ? 4 : 1;
    int nzp = split ? 2 : 1;
    float* apart = split ? (float*)(ws + OFF_PART) : a;
    float* ppart = split ? (float*)(ws + OFF_PART + PART_A_BYTES) : P0;
    int pera = (ND / 32 + nza - 1) / nza;
    int perp = (KY / 32 + nzp - 1) / nzp;

    hipLaunchKernelGGL(k_detect, dim3(1), dim3(256), 0, stream, X, flag);
    hipLaunchKernelGGL(k_gatherb, dim3(S * N), dim3(DP), 0, stream, flag, xi, X, gxb);
    hipLaunchKernelGGL(k_twg, dim3(ND / 32, 10), dim3(256), 0, stream, flag, Wg, wgt);
    hipLaunchKernelGGL(k_tws, dim3(KY / 32, 10), dim3(256), 0, stream, flag, convW, W0, wst);
    hipLaunchKernelGGL(k_yb, dim3(S), dim3(DP), 0, stream, gxb, ei, et, yb);
    hipLaunchKernelGGL(k_gemm, dim3(S / 16, 19, nza), dim3(256), 0, stream, gxb, ND, wgt, ND,
                       apart, D, D, ND / 32, pera);
    if (split)
        hipLaunchKernelGGL(k_red, dim3((S * D + 255) / 256), dim3(256), 0, stream, apart, a,
                           S * D, nza);
    hipLaunchKernelGGL(k_gemm, dim3(S / 16, 19, nzp), dim3(256), 0, stream, yb, KY, wst, KY,
                       ppart, D, D, KY / 32, perp);
    if (split)
        hipLaunchKernelGGL(k_red, dim3((S * D + 255) / 256), dim3(256), 0, stream, ppart, P0,
                           S * D, nzp);
    hipLaunchKernelGGL(k_scan, dim3(1), dim3(512), 0, stream, flag, a, P0, Ug, x1p);
    hipLaunchKernelGGL(k_logits, dim3(VP / 64), dim3(256), 0, stream, flag, x1p, lw, lb, d_out);
    hipLaunchKernelGGL(k_norm, dim3(S), dim3(512), 0, stream, flag, d_out);
}